// Round 5
// baseline (103.994 us; speedup 1.0000x reference)
//
#include <hip/hip_runtime.h>

#define TL 2048
#define TC 8
#define TK 84
#define TF 4
#define TD 4
#define TEXT 320              // tile: 256 outputs + 32 halo each side
#define SROW 352              // padded phase-major row stride (floats)
#define NFEAT (TD * TK * TF)  // 1344

__device__ __forceinline__ void count_one(
    int k, const float* __restrict__ l,
    const float4* __restrict__ biasL4, const float4 (*__restrict__ kwL4)[3],
    const unsigned long long* __restrict__ mokI, int d_idx,
    int (*__restrict__ feats)[TF], int lane)
{
    const float4 bq = biasL4[k];
    const float4 w0 = kwL4[k][0], w1 = kwL4[k][1], w2 = kwL4[k][2];
    const float wv[9] = {w0.x, w0.y, w0.z, w0.w, w1.x, w1.y, w1.z, w1.w, w2.x};
    const bool odd = ((d_idx + k) & 1) != 0;
    int c0 = 0, c1 = 0, c2 = 0, c3 = 0;
    #pragma unroll
    for (int i = 0; i < 4; ++i) {
        float r = 0.f;
        #pragma unroll
        for (int j = 0; j < 9; ++j) r = fmaf(wv[j], l[i + j], r);
        const unsigned long long mok = odd ? mokI[i] : ~0ull;
        c0 += __popcll(__ballot(r > bq.x) & mok);
        c1 += __popcll(__ballot(r > bq.y) & mok);
        c2 += __popcll(__ballot(r > bq.z) & mok);
        c3 += __popcll(__ballot(r > bq.w) & mok);
    }
    if (lane == 0) {
        feats[k][0] += c0; feats[k][1] += c1;
        feats[k][2] += c2; feats[k][3] += c3;
    }
}

// One 256-output tile. Phase-major Stab: ext pos e -> (e&(DIL-1))*PS + (e>>LD).
template <int DIL>
__device__ __forceinline__ void tile_work(
    float (*__restrict__ Stab)[SROW],
    int (*__restrict__ feats)[TF],
    const int* __restrict__ kbits,
    const float4* __restrict__ biasL4,
    const float4 (*__restrict__ kwL4)[3],
    const float* __restrict__ xb,
    int tid, int lane, int w, int P0)
{
    constexpr int LD = (DIL == 8) ? 3 : (DIL == 4) ? 2 : (DIL == 2) ? 1 : 0;
    constexpr int PS = (DIL == 1) ? 320 : (DIL == 2) ? 168 : (DIL == 4) ? 84 : 44;
    const int E0 = P0 - 32;

    // ---- build phase-major subset-sum tables (cross-lane producer) ----
    if (tid < TEXT) {
        const int e = tid;
        const int pos = E0 + e;
        float ch[8] = {0.f, 0.f, 0.f, 0.f, 0.f, 0.f, 0.f, 0.f};
        if (pos >= 0 && pos < TL) {
            const float4* xp = (const float4*)(xb + (size_t)pos * TC);
            const float4 a = xp[0], h = xp[1];
            ch[0] = a.x; ch[1] = a.y; ch[2] = a.z; ch[3] = a.w;
            ch[4] = h.x; ch[5] = h.y; ch[6] = h.z; ch[7] = h.w;
        }
        float lo[16], hi[16];
        lo[0] = 0.f; hi[0] = 0.f;
        #pragma unroll
        for (int m = 1; m < 16; ++m) lo[m] = lo[m & (m - 1)] + ch[__builtin_ctz(m)];
        #pragma unroll
        for (int m = 1; m < 16; ++m) hi[m] = hi[m & (m - 1)] + ch[4 + __builtin_ctz(m)];
        const int pe = (e & (DIL - 1)) * PS + (e >> LD);
        #pragma unroll
        for (int s = 0; s < 16; ++s) { Stab[s][pe] = lo[s]; Stab[16 + s][pe] = hi[s]; }
    }
    __syncthreads();

    // ---- per-wave: wave w owns kernels k = 8g + w ----
    const int p  = lane & (DIL - 1);
    const int jr = lane >> LD;
    const int f4b = p * (PS / 4) + (8 >> LD) - 1 + jr;

    unsigned long long mokI[4];
    #pragma unroll
    for (int i = 0; i < 4; ++i) {
        const int apos = P0 + p + (4 * jr + i) * DIL;
        mokI[i] = __ballot(apos >= 4 * DIL && apos < TL - 4 * DIL);
    }

    for (int g = 0; g < 10; g += 2) {
        const int k1 = g * 8 + w, k2 = k1 + 8;
        const int bb1 = kbits[k1], bb2 = kbits[k2];
        const float4* s1l = (const float4*)&Stab[bb1 & 15][0];
        const float4* s1h = (const float4*)&Stab[16 + (bb1 >> 4)][0];
        const float4* s2l = (const float4*)&Stab[bb2 & 15][0];
        const float4* s2h = (const float4*)&Stab[16 + (bb2 >> 4)][0];

        float4 A[3], H[3], A2[3], H2[3];
        #pragma unroll
        for (int j = 0; j < 3; ++j) { A[j] = s1l[f4b + j]; H[j] = s1h[f4b + j]; }
        #pragma unroll
        for (int j = 0; j < 3; ++j) { A2[j] = s2l[f4b + j]; H2[j] = s2h[f4b + j]; }

        float l1[12], l2[12];
        #pragma unroll
        for (int j = 0; j < 3; ++j) {
            l1[4*j+0] = A[j].x + H[j].x;  l1[4*j+1] = A[j].y + H[j].y;
            l1[4*j+2] = A[j].z + H[j].z;  l1[4*j+3] = A[j].w + H[j].w;
            l2[4*j+0] = A2[j].x + H2[j].x; l2[4*j+1] = A2[j].y + H2[j].y;
            l2[4*j+2] = A2[j].z + H2[j].z; l2[4*j+3] = A2[j].w + H2[j].w;
        }
        count_one(k1, l1, biasL4, kwL4, mokI, LD, feats, lane);
        count_one(k2, l2, biasL4, kwL4, mokI, LD, feats, lane);
    }
    // tail: kernels 80..83 on waves 0..3
    if (w < 4) {
        const int k = 80 + w;
        const int bb = kbits[k];
        const float4* sl = (const float4*)&Stab[bb & 15][0];
        const float4* sh = (const float4*)&Stab[16 + (bb >> 4)][0];
        float4 A[3], H[3];
        #pragma unroll
        for (int j = 0; j < 3; ++j) { A[j] = sl[f4b + j]; H[j] = sh[f4b + j]; }
        float l1[12];
        #pragma unroll
        for (int j = 0; j < 3; ++j) {
            l1[4*j+0] = A[j].x + H[j].x; l1[4*j+1] = A[j].y + H[j].y;
            l1[4*j+2] = A[j].z + H[j].z; l1[4*j+3] = A[j].w + H[j].w;
        }
        count_one(k, l1, biasL4, kwL4, mokI, LD, feats, lane);
    }
}

__global__ __launch_bounds__(512, 6) void mr_main(
    const float* __restrict__ x,      // [B, L, C]
    const float* __restrict__ kern,   // [K, 9]
    const float* __restrict__ cmask,  // [D, K, C]
    const float* __restrict__ bias,   // [D, K, F]
    const float* __restrict__ fstd,   // [NFEAT]
    float* __restrict__ out)          // [B, NFEAT], pre-init to -mean/std
{
    __shared__ __align__(16) float Stab[32][SROW];   // 45056 B
    __shared__ int   feats[TK][TF];
    __shared__ int   kbits[TK];
    __shared__ __align__(16) float4 biasL4[TK];
    __shared__ __align__(16) float4 kwL4[TK][3];

    const int bx = blockIdx.x;
    const int q = bx & 3, d_idx = (bx >> 2) & 3, b = bx >> 4;
    const int tid = threadIdx.x, lane = tid & 63, w = tid >> 6;
    const float* xb = x + (size_t)b * TL * TC;

    for (int kk = tid; kk < TK; kk += 512) {
        const float* cm = cmask + ((size_t)d_idx * TK + kk) * TC;
        int bits = 0;
        #pragma unroll
        for (int c = 0; c < TC; ++c) bits |= (cm[c] != 0.f) ? (1 << c) : 0;
        kbits[kk] = bits;
        const float* bp = bias + ((size_t)d_idx * TK + kk) * TF;
        biasL4[kk] = make_float4(bp[0], bp[1], bp[2], bp[3]);
        const float* kp = kern + kk * 9;
        kwL4[kk][0] = make_float4(kp[0], kp[1], kp[2], kp[3]);
        kwL4[kk][1] = make_float4(kp[4], kp[5], kp[6], kp[7]);
        kwL4[kk][2] = make_float4(kp[8], 0.f, 0.f, 0.f);
    }
    for (int i2 = tid; i2 < TK * TF; i2 += 512) ((int*)feats)[i2] = 0;
    // visibility: covered by the build->consume __syncthreads inside tile_work

    for (int t = 0; t < 2; ++t) {
        if (t) __syncthreads();   // prior tile's Stab readers done before rebuild
        const int P0 = q * 512 + t * 256;
        switch (d_idx) {
            case 0:  tile_work<1>(Stab, feats, kbits, biasL4, kwL4, xb, tid, lane, w, P0); break;
            case 1:  tile_work<2>(Stab, feats, kbits, biasL4, kwL4, xb, tid, lane, w, P0); break;
            case 2:  tile_work<4>(Stab, feats, kbits, biasL4, kwL4, xb, tid, lane, w, P0); break;
            default: tile_work<8>(Stab, feats, kbits, biasL4, kwL4, xb, tid, lane, w, P0); break;
        }
    }

    __syncthreads();
    for (int idx = tid; idx < TK * TF; idx += 512) {
        const int k = idx >> 2;
        const bool odd2 = ((d_idx + k) & 1) != 0;
        const float denom = odd2 ? (float)(TL - (8 << d_idx)) : (float)TL;
        const int fid = d_idx * (TK * TF) + idx;
        const float scale = 1.0f / (denom * fstd[fid]);
        atomicAdd(&out[(size_t)b * NFEAT + fid], (float)feats[k][idx & 3] * scale);
    }
}

__global__ void mr_init(const float* __restrict__ fmean, const float* __restrict__ fstd,
                        float* __restrict__ out) {
    const int o = blockIdx.x * 256 + threadIdx.x;
    if (o < 64 * NFEAT) {
        const int fid = o % NFEAT;
        out[o] = -fmean[fid] / fstd[fid];
    }
}

extern "C" void kernel_launch(void* const* d_in, const int* in_sizes, int n_in,
                              void* d_out, int out_size, void* d_ws, size_t ws_size,
                              hipStream_t stream) {
    const float* x     = (const float*)d_in[0];
    const float* kern  = (const float*)d_in[1];
    const float* cmask = (const float*)d_in[2];
    const float* bias  = (const float*)d_in[3];
    const float* fmean = (const float*)d_in[4];
    const float* fstd  = (const float*)d_in[5];
    float* out = (float*)d_out;

    hipLaunchKernelGGL(mr_init, dim3((64 * NFEAT + 255) / 256), dim3(256), 0, stream,
                       fmean, fstd, out);
    hipLaunchKernelGGL(mr_main, dim3(64 * TD * 4), dim3(512), 0, stream,
                       x, kern, cmask, bias, fstd, out);
}

// Round 6
// 97.224 us; speedup vs baseline: 1.0696x; 1.0696x over previous
//
#include <hip/hip_runtime.h>

#define TL 2048
#define TC 8
#define TK 84
#define TF 4
#define TD 4
#define TEXT 320              // tile: 256 outputs + 32 halo each side
#define SROW 352              // padded phase-major row stride (floats)
#define NFEAT (TD * TK * TF)  // 1344

__device__ __forceinline__ void count_one(
    int k, const float* __restrict__ l,
    const float4* __restrict__ biasL4, const float4 (*__restrict__ kwL4)[3],
    const unsigned long long* __restrict__ mokI, int d_idx,
    int (*__restrict__ feats)[TF], int lane)
{
    const float4 bq = biasL4[k];
    const float4 w0 = kwL4[k][0], w1 = kwL4[k][1], w2 = kwL4[k][2];
    const float wv[9] = {w0.x, w0.y, w0.z, w0.w, w1.x, w1.y, w1.z, w1.w, w2.x};
    const bool odd = ((d_idx + k) & 1) != 0;
    int c0 = 0, c1 = 0, c2 = 0, c3 = 0;
    #pragma unroll
    for (int i = 0; i < 4; ++i) {
        float r = 0.f;
        #pragma unroll
        for (int j = 0; j < 9; ++j) r = fmaf(wv[j], l[i + j], r);
        const unsigned long long mok = odd ? mokI[i] : ~0ull;
        c0 += __popcll(__ballot(r > bq.x) & mok);
        c1 += __popcll(__ballot(r > bq.y) & mok);
        c2 += __popcll(__ballot(r > bq.z) & mok);
        c3 += __popcll(__ballot(r > bq.w) & mok);
    }
    if (lane == 0) {
        feats[k][0] += c0; feats[k][1] += c1;
        feats[k][2] += c2; feats[k][3] += c3;
    }
}

// One 256-output tile. Phase-major Stab: ext pos e -> (e&(DIL-1))*PS + (e>>LD).
template <int DIL>
__device__ __forceinline__ void tile_work(
    float (*__restrict__ Stab)[SROW],
    int (*__restrict__ feats)[TF],
    const int* __restrict__ kbits,
    const float4* __restrict__ biasL4,
    const float4 (*__restrict__ kwL4)[3],
    const float* __restrict__ xb,
    int tid, int lane, int w, int P0)
{
    constexpr int LD = (DIL == 8) ? 3 : (DIL == 4) ? 2 : (DIL == 2) ? 1 : 0;
    constexpr int PS = (DIL == 1) ? 320 : (DIL == 2) ? 168 : (DIL == 4) ? 84 : 44;
    const int E0 = P0 - 32;

    // ---- build phase-major subset-sum tables (cross-lane producer) ----
    if (tid < TEXT) {
        const int e = tid;
        const int pos = E0 + e;
        float ch[8] = {0.f, 0.f, 0.f, 0.f, 0.f, 0.f, 0.f, 0.f};
        if (pos >= 0 && pos < TL) {
            const float4* xp = (const float4*)(xb + (size_t)pos * TC);
            const float4 a = xp[0], h = xp[1];
            ch[0] = a.x; ch[1] = a.y; ch[2] = a.z; ch[3] = a.w;
            ch[4] = h.x; ch[5] = h.y; ch[6] = h.z; ch[7] = h.w;
        }
        float lo[16], hi[16];
        lo[0] = 0.f; hi[0] = 0.f;
        #pragma unroll
        for (int m = 1; m < 16; ++m) lo[m] = lo[m & (m - 1)] + ch[__builtin_ctz(m)];
        #pragma unroll
        for (int m = 1; m < 16; ++m) hi[m] = hi[m & (m - 1)] + ch[4 + __builtin_ctz(m)];
        const int pe = (e & (DIL - 1)) * PS + (e >> LD);
        #pragma unroll
        for (int s = 0; s < 16; ++s) { Stab[s][pe] = lo[s]; Stab[16 + s][pe] = hi[s]; }
    }
    __syncthreads();

    // ---- per-wave: wave w owns kernels k = 8g + w ----
    const int p  = lane & (DIL - 1);
    const int jr = lane >> LD;
    const int f4b = p * (PS / 4) + (8 >> LD) - 1 + jr;

    unsigned long long mokI[4];
    #pragma unroll
    for (int i = 0; i < 4; ++i) {
        const int apos = P0 + p + (4 * jr + i) * DIL;
        mokI[i] = __ballot(apos >= 4 * DIL && apos < TL - 4 * DIL);
    }

    for (int g = 0; g < 10; g += 2) {
        const int k1 = g * 8 + w, k2 = k1 + 8;
        const int bb1 = kbits[k1], bb2 = kbits[k2];
        const float4* s1l = (const float4*)&Stab[bb1 & 15][0];
        const float4* s1h = (const float4*)&Stab[16 + (bb1 >> 4)][0];
        const float4* s2l = (const float4*)&Stab[bb2 & 15][0];
        const float4* s2h = (const float4*)&Stab[16 + (bb2 >> 4)][0];

        float4 A[3], H[3], A2[3], H2[3];
        #pragma unroll
        for (int j = 0; j < 3; ++j) { A[j] = s1l[f4b + j]; H[j] = s1h[f4b + j]; }
        #pragma unroll
        for (int j = 0; j < 3; ++j) { A2[j] = s2l[f4b + j]; H2[j] = s2h[f4b + j]; }

        float l1[12], l2[12];
        #pragma unroll
        for (int j = 0; j < 3; ++j) {
            l1[4*j+0] = A[j].x + H[j].x;  l1[4*j+1] = A[j].y + H[j].y;
            l1[4*j+2] = A[j].z + H[j].z;  l1[4*j+3] = A[j].w + H[j].w;
            l2[4*j+0] = A2[j].x + H2[j].x; l2[4*j+1] = A2[j].y + H2[j].y;
            l2[4*j+2] = A2[j].z + H2[j].z; l2[4*j+3] = A2[j].w + H2[j].w;
        }
        count_one(k1, l1, biasL4, kwL4, mokI, LD, feats, lane);
        count_one(k2, l2, biasL4, kwL4, mokI, LD, feats, lane);
    }
    // tail: kernels 80..83 on waves 0..3
    if (w < 4) {
        const int k = 80 + w;
        const int bb = kbits[k];
        const float4* sl = (const float4*)&Stab[bb & 15][0];
        const float4* sh = (const float4*)&Stab[16 + (bb >> 4)][0];
        float4 A[3], H[3];
        #pragma unroll
        for (int j = 0; j < 3; ++j) { A[j] = sl[f4b + j]; H[j] = sh[f4b + j]; }
        float l1[12];
        #pragma unroll
        for (int j = 0; j < 3; ++j) {
            l1[4*j+0] = A[j].x + H[j].x; l1[4*j+1] = A[j].y + H[j].y;
            l1[4*j+2] = A[j].z + H[j].z; l1[4*j+3] = A[j].w + H[j].w;
        }
        count_one(k, l1, biasL4, kwL4, mokI, LD, feats, lane);
    }
}

__global__ __launch_bounds__(512, 4) void mr_main(
    const float* __restrict__ x,      // [B, L, C]
    const float* __restrict__ kern,   // [K, 9]
    const float* __restrict__ cmask,  // [D, K, C]
    const float* __restrict__ bias,   // [D, K, F]
    const float* __restrict__ fstd,   // [NFEAT]
    float* __restrict__ out)          // [B, NFEAT], pre-init to -mean/std
{
    __shared__ __align__(16) float Stab[32][SROW];   // 45056 B
    __shared__ int   feats[TK][TF];
    __shared__ int   kbits[TK];
    __shared__ __align__(16) float4 biasL4[TK];
    __shared__ __align__(16) float4 kwL4[TK][3];

    const int bx = blockIdx.x;
    const int q = bx & 3, d_idx = (bx >> 2) & 3, b = bx >> 4;
    const int tid = threadIdx.x, lane = tid & 63, w = tid >> 6;
    const float* xb = x + (size_t)b * TL * TC;

    for (int kk = tid; kk < TK; kk += 512) {
        const float* cm = cmask + ((size_t)d_idx * TK + kk) * TC;
        int bits = 0;
        #pragma unroll
        for (int c = 0; c < TC; ++c) bits |= (cm[c] != 0.f) ? (1 << c) : 0;
        kbits[kk] = bits;
        const float* bp = bias + ((size_t)d_idx * TK + kk) * TF;
        biasL4[kk] = make_float4(bp[0], bp[1], bp[2], bp[3]);
        const float* kp = kern + kk * 9;
        kwL4[kk][0] = make_float4(kp[0], kp[1], kp[2], kp[3]);
        kwL4[kk][1] = make_float4(kp[4], kp[5], kp[6], kp[7]);
        kwL4[kk][2] = make_float4(kp[8], 0.f, 0.f, 0.f);
    }
    for (int i2 = tid; i2 < TK * TF; i2 += 512) ((int*)feats)[i2] = 0;
    // visibility: covered by the build->consume __syncthreads inside tile_work

    for (int t = 0; t < 2; ++t) {
        if (t) __syncthreads();   // prior tile's Stab readers done before rebuild
        const int P0 = q * 512 + t * 256;
        switch (d_idx) {
            case 0:  tile_work<1>(Stab, feats, kbits, biasL4, kwL4, xb, tid, lane, w, P0); break;
            case 1:  tile_work<2>(Stab, feats, kbits, biasL4, kwL4, xb, tid, lane, w, P0); break;
            case 2:  tile_work<4>(Stab, feats, kbits, biasL4, kwL4, xb, tid, lane, w, P0); break;
            default: tile_work<8>(Stab, feats, kbits, biasL4, kwL4, xb, tid, lane, w, P0); break;
        }
    }

    __syncthreads();
    for (int idx = tid; idx < TK * TF; idx += 512) {
        const int k = idx >> 2;
        const bool odd2 = ((d_idx + k) & 1) != 0;
        const float denom = odd2 ? (float)(TL - (8 << d_idx)) : (float)TL;
        const int fid = d_idx * (TK * TF) + idx;
        const float scale = 1.0f / (denom * fstd[fid]);
        atomicAdd(&out[(size_t)b * NFEAT + fid], (float)feats[k][idx & 3] * scale);
    }
}

__global__ void mr_init(const float* __restrict__ fmean, const float* __restrict__ fstd,
                        float* __restrict__ out) {
    const int o = blockIdx.x * 256 + threadIdx.x;
    if (o < 64 * NFEAT) {
        const int fid = o % NFEAT;
        out[o] = -fmean[fid] / fstd[fid];
    }
}

extern "C" void kernel_launch(void* const* d_in, const int* in_sizes, int n_in,
                              void* d_out, int out_size, void* d_ws, size_t ws_size,
                              hipStream_t stream) {
    const float* x     = (const float*)d_in[0];
    const float* kern  = (const float*)d_in[1];
    const float* cmask = (const float*)d_in[2];
    const float* bias  = (const float*)d_in[3];
    const float* fmean = (const float*)d_in[4];
    const float* fstd  = (const float*)d_in[5];
    float* out = (float*)d_out;

    hipLaunchKernelGGL(mr_init, dim3((64 * NFEAT + 255) / 256), dim3(256), 0, stream,
                       fmean, fstd, out);
    hipLaunchKernelGGL(mr_main, dim3(64 * TD * 4), dim3(512), 0, stream,
                       x, kern, cmask, bias, fstd, out);
}

// Round 7
// 56.312 us; speedup vs baseline: 1.8467x; 1.7265x over previous
//
#include <hip/hip_runtime.h>

#define TL 2048
#define TC 8
#define TK 84
#define TF 4
#define TD 4
#define TEXT 320              // tile: 256 outputs + 32 halo each side
#define SROWE 352             // bf16 elements per table row
#define NFEAT (TD * TK * TF)  // 1344

typedef unsigned short u16;
typedef unsigned int u32;

__device__ __forceinline__ u16 bf16rne(float f) {
    u32 u = __builtin_bit_cast(u32, f);
    u += 0x7fffu + ((u >> 16) & 1u);
    return (u16)(u >> 16);
}
__device__ __forceinline__ float bflo(u32 u) { return __builtin_bit_cast(float, u << 16); }
__device__ __forceinline__ float bfhi(u32 u) { return __builtin_bit_cast(float, u & 0xffff0000u); }

// One 256-output tile. Phase-major bf16 Stab: ext pos e -> (e&(DIL-1))*PS + (e>>LD).
template <int DIL>
__device__ __forceinline__ void tile_work(
    u16 (*__restrict__ Stab)[SROWE],
    int (*__restrict__ feats)[TF],
    const float* __restrict__ cmask,   // [D,K,C] global
    const float* __restrict__ kern,    // [K,9]   global
    const float* __restrict__ bias,    // [D,K,F] global
    const float* __restrict__ xb,
    int d_idx, int tid, int lane, int w, int P0)
{
    constexpr int LD = (DIL == 8) ? 3 : (DIL == 4) ? 2 : (DIL == 2) ? 1 : 0;
    constexpr int PS = (DIL == 1) ? 320 : (DIL == 2) ? 168 : (DIL == 4) ? 84 : 44;
    const int E0 = P0 - 32;

    // ---- build phase-major bf16 subset-sum tables ----
    if (tid < TEXT) {
        const int e = tid;
        const int pos = E0 + e;
        float ch[8] = {0.f, 0.f, 0.f, 0.f, 0.f, 0.f, 0.f, 0.f};
        if (pos >= 0 && pos < TL) {
            const float4* xp = (const float4*)(xb + (size_t)pos * TC);
            const float4 a = xp[0], h = xp[1];
            ch[0] = a.x; ch[1] = a.y; ch[2] = a.z; ch[3] = a.w;
            ch[4] = h.x; ch[5] = h.y; ch[6] = h.z; ch[7] = h.w;
        }
        float lo[16], hi[16];
        lo[0] = 0.f; hi[0] = 0.f;
        #pragma unroll
        for (int m = 1; m < 16; ++m) lo[m] = lo[m & (m - 1)] + ch[__builtin_ctz(m)];
        #pragma unroll
        for (int m = 1; m < 16; ++m) hi[m] = hi[m & (m - 1)] + ch[4 + __builtin_ctz(m)];
        const int pe = (e & (DIL - 1)) * PS + (e >> LD);
        #pragma unroll
        for (int s = 0; s < 16; ++s) {
            Stab[s][pe]      = bf16rne(lo[s]);
            Stab[16 + s][pe] = bf16rne(hi[s]);
        }
    }
    __syncthreads();

    // ---- per-wave kernel loop: wave w owns k = 8g + w (waves 0-3 get one extra) ----
    const int p  = lane & (DIL - 1);
    const int jr = lane >> LD;
    const int eoff = p * PS + (32 >> LD) - 4 + 4 * jr;   // first needed element

    unsigned long long mokI[4];
    #pragma unroll
    for (int i = 0; i < 4; ++i) {
        const int apos = P0 + p + (4 * jr + i) * DIL;
        mokI[i] = __ballot(apos >= 4 * DIL && apos < TL - 4 * DIL);
    }

    const int nk = (w < 4) ? 11 : 10;
    for (int g = 0; g < nk; ++g) {
        const int uk = __builtin_amdgcn_readfirstlane(g * 8 + w);

        // -- wave-uniform constants via scalar loads (no LDS) --
        const int* cmi = (const int*)(cmask + ((size_t)d_idx * TK + uk) * TC);
        int bits = 0;
        #pragma unroll
        for (int c = 0; c < TC; ++c) bits |= (cmi[c] != 0) ? (1 << c) : 0;
        float wv[9];
        #pragma unroll
        for (int j = 0; j < 9; ++j) wv[j] = kern[uk * 9 + j];
        const float4 bq = *(const float4*)(bias + ((size_t)d_idx * TK + uk) * TF);
        const bool odd = ((d_idx + uk) & 1) != 0;

        // -- 12-element windows, bf16, 3+3 ds_read_b64 --
        const u16* rl = &Stab[bits & 15][0];
        const u16* rh = &Stab[16 + (bits >> 4)][0];
        const uint2 La0 = *(const uint2*)(rl + eoff);
        const uint2 La1 = *(const uint2*)(rl + eoff + 4);
        const uint2 La2 = *(const uint2*)(rl + eoff + 8);
        const uint2 Lh0 = *(const uint2*)(rh + eoff);
        const uint2 Lh1 = *(const uint2*)(rh + eoff + 4);
        const uint2 Lh2 = *(const uint2*)(rh + eoff + 8);

        float l[12];
        l[0]  = bflo(La0.x) + bflo(Lh0.x);  l[1]  = bfhi(La0.x) + bfhi(Lh0.x);
        l[2]  = bflo(La0.y) + bflo(Lh0.y);  l[3]  = bfhi(La0.y) + bfhi(Lh0.y);
        l[4]  = bflo(La1.x) + bflo(Lh1.x);  l[5]  = bfhi(La1.x) + bfhi(Lh1.x);
        l[6]  = bflo(La1.y) + bflo(Lh1.y);  l[7]  = bfhi(La1.y) + bfhi(Lh1.y);
        l[8]  = bflo(La2.x) + bflo(Lh2.x);  l[9]  = bfhi(La2.x) + bfhi(Lh2.x);
        l[10] = bflo(La2.y) + bflo(Lh2.y);  l[11] = bfhi(La2.y) + bfhi(Lh2.y);

        int c0 = 0, c1 = 0, c2 = 0, c3 = 0;
        #pragma unroll
        for (int i = 0; i < 4; ++i) {
            float r = 0.f;
            #pragma unroll
            for (int j = 0; j < 9; ++j) r = fmaf(wv[j], l[i + j], r);
            const unsigned long long mok = odd ? mokI[i] : ~0ull;
            c0 += __popcll(__ballot(r > bq.x) & mok);
            c1 += __popcll(__ballot(r > bq.y) & mok);
            c2 += __popcll(__ballot(r > bq.z) & mok);
            c3 += __popcll(__ballot(r > bq.w) & mok);
        }
        if (lane == 0) {
            feats[uk][0] += c0; feats[uk][1] += c1;
            feats[uk][2] += c2; feats[uk][3] += c3;
        }
    }
}

__global__ __launch_bounds__(512, 4) void mr_main(
    const float* __restrict__ x,      // [B, L, C]
    const float* __restrict__ kern,   // [K, 9]
    const float* __restrict__ cmask,  // [D, K, C]
    const float* __restrict__ bias,   // [D, K, F]
    const float* __restrict__ fstd,   // [NFEAT]
    float* __restrict__ out)          // [B, NFEAT], pre-init to -mean/std
{
    __shared__ __align__(16) u16 Stab[32][SROWE];   // 22528 B
    __shared__ int feats[TK][TF];                   // 1344 B

    const int bx = blockIdx.x;
    const int q = bx & 3, d_idx = (bx >> 2) & 3, b = bx >> 4;
    const int tid = threadIdx.x, lane = tid & 63, w = tid >> 6;
    const float* xb = x + (size_t)b * TL * TC;

    for (int i2 = tid; i2 < TK * TF; i2 += 512) ((int*)feats)[i2] = 0;
    // visibility: covered by the build->consume __syncthreads inside tile_work

    for (int t = 0; t < 2; ++t) {
        if (t) __syncthreads();   // prior tile's Stab readers done before rebuild
        const int P0 = q * 512 + t * 256;
        switch (d_idx) {
            case 0:  tile_work<1>(Stab, feats, cmask, kern, bias, xb, d_idx, tid, lane, w, P0); break;
            case 1:  tile_work<2>(Stab, feats, cmask, kern, bias, xb, d_idx, tid, lane, w, P0); break;
            case 2:  tile_work<4>(Stab, feats, cmask, kern, bias, xb, d_idx, tid, lane, w, P0); break;
            default: tile_work<8>(Stab, feats, cmask, kern, bias, xb, d_idx, tid, lane, w, P0); break;
        }
    }

    __syncthreads();
    for (int idx = tid; idx < TK * TF; idx += 512) {
        const int k = idx >> 2;
        const bool odd2 = ((d_idx + k) & 1) != 0;
        const float denom = odd2 ? (float)(TL - (8 << d_idx)) : (float)TL;
        const int fid = d_idx * (TK * TF) + idx;
        const float scale = 1.0f / (denom * fstd[fid]);
        atomicAdd(&out[(size_t)b * NFEAT + fid], (float)feats[k][idx & 3] * scale);
    }
}

__global__ void mr_init(const float* __restrict__ fmean, const float* __restrict__ fstd,
                        float* __restrict__ out) {
    const int o = blockIdx.x * 256 + threadIdx.x;
    if (o < 64 * NFEAT) {
        const int fid = o % NFEAT;
        out[o] = -fmean[fid] / fstd[fid];
    }
}

extern "C" void kernel_launch(void* const* d_in, const int* in_sizes, int n_in,
                              void* d_out, int out_size, void* d_ws, size_t ws_size,
                              hipStream_t stream) {
    const float* x     = (const float*)d_in[0];
    const float* kern  = (const float*)d_in[1];
    const float* cmask = (const float*)d_in[2];
    const float* bias  = (const float*)d_in[3];
    const float* fmean = (const float*)d_in[4];
    const float* fstd  = (const float*)d_in[5];
    float* out = (float*)d_out;

    hipLaunchKernelGGL(mr_init, dim3((64 * NFEAT + 255) / 256), dim3(256), 0, stream,
                       fmean, fstd, out);
    hipLaunchKernelGGL(mr_main, dim3(64 * TD * 4), dim3(512), 0, stream,
                       x, kern, cmask, bias, fstd, out);
}

// Round 9
// 42.772 us; speedup vs baseline: 2.4314x; 1.3166x over previous
//
#include <hip/hip_runtime.h>

#define TL 2048
#define TC 8
#define TK 84
#define TF 4
#define TD 4
#define ROWU 288              // u32 per table row (576 fp16 elements)
#define NFEAT (TD * TK * TF)  // 1344

typedef unsigned short u16;
typedef unsigned int u32;
typedef unsigned long long u64;
typedef _Float16 h2 __attribute__((ext_vector_type(2)));   // arithmetic-facing
typedef __fp16   f2 __attribute__((ext_vector_type(2)));   // builtin-facing

__device__ __forceinline__ u32 pkrtz(float a, float b) {
    return __builtin_bit_cast(u32, __builtin_amdgcn_cvt_pkrtz(a, b));
}
__device__ __forceinline__ float fdot2(h2 a, h2 b, float c) {
    return __builtin_amdgcn_fdot2(__builtin_bit_cast(f2, a),
                                  __builtin_bit_cast(f2, b), c, false);
}

// 8-byte-pair XOR swizzle, applied identically on write (b32 pair) and read (b64).
__device__ __forceinline__ int swzp(int P) { return P ^ (((P >> 4) & 7) << 1); }

template <int DIL>
__device__ __forceinline__ void work(
    u32* __restrict__ S, int (*__restrict__ feats)[TF],
    const float* __restrict__ cmask, const float* __restrict__ kern,
    const float* __restrict__ bias, const float* __restrict__ xb,
    int d_idx, int tid, int lane, int w, int q)
{
    constexpr int LD = (DIL == 8) ? 3 : (DIL == 4) ? 2 : (DIL == 2) ? 1 : 0;
    constexpr int PS = 576 >> LD;          // per-phase row length (fp16 elements)
    const int E0 = q * 512 - 32;

    // ---- build: phase-major fp16 subset-sum tables, 2 positions/thread ----
    if (tid < 288) {
        const int u = tid;                  // u32 slot within row
        const int p = (2 * u) / PS, t = (2 * u) % PS;
        const int e0 = t * DIL + p;
        float ch0[8] = {0,0,0,0,0,0,0,0}, ch1[8] = {0,0,0,0,0,0,0,0};
        const int pos0 = E0 + e0, pos1 = pos0 + DIL;
        if (pos0 >= 0 && pos0 < TL) {
            const float4* xp = (const float4*)(xb + (size_t)pos0 * TC);
            const float4 a = xp[0], h = xp[1];
            ch0[0]=a.x; ch0[1]=a.y; ch0[2]=a.z; ch0[3]=a.w;
            ch0[4]=h.x; ch0[5]=h.y; ch0[6]=h.z; ch0[7]=h.w;
        }
        if (pos1 >= 0 && pos1 < TL) {
            const float4* xp = (const float4*)(xb + (size_t)pos1 * TC);
            const float4 a = xp[0], h = xp[1];
            ch1[0]=a.x; ch1[1]=a.y; ch1[2]=a.z; ch1[3]=a.w;
            ch1[4]=h.x; ch1[5]=h.y; ch1[6]=h.z; ch1[7]=h.w;
        }
        float lo0[16], hi0[16], lo1[16], hi1[16];
        lo0[0]=0.f; hi0[0]=0.f; lo1[0]=0.f; hi1[0]=0.f;
        #pragma unroll
        for (int m = 1; m < 16; ++m) {
            const int z = __builtin_ctz(m), r = m & (m - 1);
            lo0[m]=lo0[r]+ch0[z];   hi0[m]=hi0[r]+ch0[4+z];
            lo1[m]=lo1[r]+ch1[z];   hi1[m]=hi1[r]+ch1[4+z];
        }
        u32* Wp = S + ((swzp(u >> 1) << 1) | (u & 1));
        #pragma unroll
        for (int s = 0; s < 16; ++s) {
            Wp[s * ROWU]        = pkrtz(lo0[s], lo1[s]);
            Wp[(16 + s) * ROWU] = pkrtz(hi0[s], hi1[s]);
        }
    }
    __syncthreads();

    // ---- consume: wave w owns kernels k = 8g + w; 8 outputs/lane ----
    const int p  = lane & (DIL - 1);
    const int jr = lane >> LD;
    const int eoff = p * PS + (32 >> LD) - 4 + 8 * jr;   // fp16-element offset, mult of 4
    int offs[4];
    #pragma unroll
    for (int m = 0; m < 4; ++m) offs[m] = swzp((eoff >> 2) + m) * 8;  // byte offsets

    u64 mok[8];
    #pragma unroll
    for (int i = 0; i < 8; ++i) {
        const int apos = q * 512 + p + (8 * jr + i) * DIL;
        mok[i] = __ballot(apos >= 4 * DIL && apos < TL - 4 * DIL);
    }

    const int nk = (w < 4) ? 11 : 10;
    for (int g = 0; g < nk; ++g) {
        const int uk = __builtin_amdgcn_readfirstlane(g * 8 + w);

        const int* cmi = (const int*)(cmask + ((size_t)d_idx * TK + uk) * TC);
        int bits = 0;
        #pragma unroll
        for (int c = 0; c < TC; ++c) bits |= (cmi[c] != 0) ? (1 << c) : 0;

        float wf[9];
        #pragma unroll
        for (int j = 0; j < 9; ++j) wf[j] = kern[uk * 9 + j];
        h2 wp[4];
        #pragma unroll
        for (int j = 0; j < 4; ++j) wp[j] = __builtin_bit_cast(h2, pkrtz(wf[2*j], wf[2*j+1]));
        const float w8 = wf[8];
        const float4 bq = *(const float4*)(bias + ((size_t)d_idx * TK + uk) * TF);
        const bool odd = ((d_idx + uk) & 1) != 0;

        const char* BL = (const char*)(S + (bits & 15) * ROWU);
        const char* BH = (const char*)(S + (16 + (bits >> 4)) * ROWU);
        uint2 lo[4], hi[4];
        #pragma unroll
        for (int m = 0; m < 4; ++m) lo[m] = *(const uint2*)(BL + offs[m]);
        #pragma unroll
        for (int m = 0; m < 4; ++m) hi[m] = *(const uint2*)(BH + offs[m]);

        h2 s8[8]; u32 su[8];
        #pragma unroll
        for (int m = 0; m < 4; ++m) {
            s8[2*m]   = __builtin_bit_cast(h2, lo[m].x) + __builtin_bit_cast(h2, hi[m].x);
            s8[2*m+1] = __builtin_bit_cast(h2, lo[m].y) + __builtin_bit_cast(h2, hi[m].y);
            su[2*m]   = __builtin_bit_cast(u32, s8[2*m]);
            su[2*m+1] = __builtin_bit_cast(u32, s8[2*m+1]);
        }
        h2 t8[7];
        #pragma unroll
        for (int m = 0; m < 7; ++m)
            t8[m] = __builtin_bit_cast(h2, __builtin_amdgcn_alignbit(su[m+1], su[m], 16));

        int c0 = 0, c1 = 0, c2 = 0, c3 = 0;
        #pragma unroll
        for (int i = 0; i < 8; ++i) {
            const int c = i >> 1;
            const float tl = (i & 1) ? (float)s8[c + 4].y : (float)s8[c + 4].x;
            float r = w8 * tl;
            if (i & 1) {
                r = fdot2(t8[c],   wp[0], r);
                r = fdot2(t8[c+1], wp[1], r);
                r = fdot2(t8[c+2], wp[2], r);
                r = fdot2(t8[c+3], wp[3], r);
            } else {
                r = fdot2(s8[c],   wp[0], r);
                r = fdot2(s8[c+1], wp[1], r);
                r = fdot2(s8[c+2], wp[2], r);
                r = fdot2(s8[c+3], wp[3], r);
            }
            const u64 mo = odd ? mok[i] : ~0ull;
            c0 += __popcll(__ballot(r > bq.x) & mo);
            c1 += __popcll(__ballot(r > bq.y) & mo);
            c2 += __popcll(__ballot(r > bq.z) & mo);
            c3 += __popcll(__ballot(r > bq.w) & mo);
        }
        if (lane == 0) {
            feats[uk][0] += c0; feats[uk][1] += c1;
            feats[uk][2] += c2; feats[uk][3] += c3;
        }
    }
}

__global__ __launch_bounds__(512, 4) void mr_main(
    const float* __restrict__ x,      // [B, L, C]
    const float* __restrict__ kern,   // [K, 9]
    const float* __restrict__ cmask,  // [D, K, C]
    const float* __restrict__ bias,   // [D, K, F]
    const float* __restrict__ fstd,   // [NFEAT]
    float* __restrict__ out)          // [B, NFEAT], pre-init to -mean/std
{
    __shared__ __align__(16) u32 S[32 * ROWU];   // 36864 B fp16 tables
    __shared__ int feats[TK][TF];                // 1344 B

    const int bx = blockIdx.x;
    const int q = bx & 3, d_idx = (bx >> 2) & 3, b = bx >> 4;
    const int tid = threadIdx.x, lane = tid & 63, w = tid >> 6;
    const float* xb = x + (size_t)b * TL * TC;

    for (int i2 = tid; i2 < TK * TF; i2 += 512) ((int*)feats)[i2] = 0;
    // feats-init visibility: covered by the build->consume __syncthreads in work()

    switch (d_idx) {
        case 0:  work<1>(S, feats, cmask, kern, bias, xb, d_idx, tid, lane, w, q); break;
        case 1:  work<2>(S, feats, cmask, kern, bias, xb, d_idx, tid, lane, w, q); break;
        case 2:  work<4>(S, feats, cmask, kern, bias, xb, d_idx, tid, lane, w, q); break;
        default: work<8>(S, feats, cmask, kern, bias, xb, d_idx, tid, lane, w, q); break;
    }

    __syncthreads();
    for (int idx = tid; idx < TK * TF; idx += 512) {
        const int k = idx >> 2;
        const bool odd2 = ((d_idx + k) & 1) != 0;
        const float denom = odd2 ? (float)(TL - (8 << d_idx)) : (float)TL;
        const int fid = d_idx * (TK * TF) + idx;
        const float scale = 1.0f / (denom * fstd[fid]);
        atomicAdd(&out[(size_t)b * NFEAT + fid], (float)feats[k][idx & 3] * scale);
    }
}

__global__ void mr_init(const float* __restrict__ fmean, const float* __restrict__ fstd,
                        float* __restrict__ out) {
    const int o = blockIdx.x * 256 + threadIdx.x;
    if (o < 64 * NFEAT) {
        const int fid = o % NFEAT;
        out[o] = -fmean[fid] / fstd[fid];
    }
}

extern "C" void kernel_launch(void* const* d_in, const int* in_sizes, int n_in,
                              void* d_out, int out_size, void* d_ws, size_t ws_size,
                              hipStream_t stream) {
    const float* x     = (const float*)d_in[0];
    const float* kern  = (const float*)d_in[1];
    const float* cmask = (const float*)d_in[2];
    const float* bias  = (const float*)d_in[3];
    const float* fmean = (const float*)d_in[4];
    const float* fstd  = (const float*)d_in[5];
    float* out = (float*)d_out;

    hipLaunchKernelGGL(mr_init, dim3((64 * NFEAT + 255) / 256), dim3(256), 0, stream,
                       fmean, fstd, out);
    hipLaunchKernelGGL(mr_main, dim3(64 * TD * 4), dim3(512), 0, stream,
                       x, kern, cmask, bias, fstd, out);
}